// Round 3
// baseline (43704.996 us; speedup 1.0000x reference)
//
#include <hip/hip_runtime.h>
#include <math.h>

#define V      100000
#define H      256
#define T      64
#define KTOP   10
#define NBLK   1024
#define RPB    98       // 1024*98 = 100352 >= V
#define NCH    64       // chain blocks
#define SENT_I 0x7ffff000
#define NEGBIG (-3.0e38f)

struct Params {
  const float *ui, *mask, *emb, *Wih, *bih, *bhh, *fcW, *fcb, *valW, *valb, *fgcW;
  const float *pm, *c1;
  float *x1, *x2, *cellg;
  float *invS, *sign_slot; int *sel_slot;
  float *tkv0, *tkv1; int *tki0, *tki1;
  float *sp0, *sp1;
  unsigned *grp, *relayf, *cellrdy, *bc, *cd;
  float *probs, *out_sel, *out_val, *out_hit, *out_fh;
};

__device__ __forceinline__ float dot4(float4 a, float4 b) {
  return a.x*b.x + a.y*b.y + a.z*b.z + a.w*b.w;
}
__device__ __forceinline__ float sigm(float x) { return 1.0f / (1.0f + expf(-x)); }
__device__ __forceinline__ void amax64(float& v, int& i) {
#pragma unroll
  for (int off = 32; off > 0; off >>= 1) {
    float vo = __shfl_xor(v, off); int io = __shfl_xor(i, off);
    if (vo > v || (vo == v && io < i)) { v = vo; i = io; }
  }
}
__device__ __forceinline__ float sum64(float p) {
#pragma unroll
  for (int off = 32; off > 0; off >>= 1) p += __shfl_xor(p, off);
  return p;
}

__global__ void init_sync(unsigned* s) {
  int i = blockIdx.x * 256 + threadIdx.x;
  if (i < 2144) s[i] = 0u;
}

// proc_mem[h] = tanh(dot(mem, mem_W[h,:]))
__global__ __launch_bounds__(256) void pm_kernel(const float* __restrict__ mem,
                                                 const float* __restrict__ memW,
                                                 float* __restrict__ pm) {
  const int h = blockIdx.x, tid = threadIdx.x;
  const int w = tid >> 6, lane = tid & 63;
  __shared__ float red[4];
  const float4* m4 = (const float4*)mem;
  const float4* w4 = (const float4*)(memW + (size_t)h * V);
  float acc = 0.f;
#pragma unroll 4
  for (int i = tid; i < V / 4; i += 256) {
    float4 a = m4[i], b = w4[i];
    acc += a.x * b.x + a.y * b.y + a.z * b.z + a.w * b.w;
  }
  acc = sum64(acc);
  if (lane == 0) red[w] = acc;
  __syncthreads();
  if (tid == 0) pm[h] = tanhf(red[0] + red[1] + red[2] + red[3]);
}

// c1[h] = -(dot(pm, fg_mem_W[h,:]) + fg_mem_b[h])
__global__ __launch_bounds__(256) void c1_kernel(const float* __restrict__ pm,
                                                 const float* __restrict__ fgmW,
                                                 const float* __restrict__ fgmb,
                                                 float* __restrict__ c1) {
  __shared__ __align__(16) float pm_s[H];
  const int tid = threadIdx.x;
  pm_s[tid] = pm[tid];
  __syncthreads();
  const float4* p4 = (const float4*)pm_s;
  const float4* r4 = (const float4*)(fgmW + (size_t)tid * H);
  float acc = 0.f;
#pragma unroll 4
  for (int j = 0; j < H / 4; ++j) {
    float4 a = p4[j], b = r4[j];
    acc += a.x * b.x + a.y * b.y + a.z * b.z + a.w * b.w;
  }
  c1[tid] = -(acc + fgmb[tid]);
}

__global__ __launch_bounds__(256, 4) void step_kernel(Params P) {
  const int b = blockIdx.x, tid = threadIdx.x;
  const int w = tid >> 6, lane = tid & 63;
  const int lane16 = tid & 15, qw = tid >> 4;
  const int rowbase = b * RPB;

  __shared__ __align__(16) float cell_s[H];
  __shared__ float e_s[RPB], m_s[RPB], hist_s[RPB], fcb_s[RPB];
  __shared__ float wtv[2 * KTOP]; __shared__ int wti[2 * KTOP];
  __shared__ float xwv[4]; __shared__ int xwi[4];
  __shared__ float red4[4];
  __shared__ int g10i[KTOP];
  __shared__ int sel_sh; __shared__ float sign_sh;

  for (int i = tid; i < RPB; i += 256) {
    int r = rowbase + i;
    hist_s[i] = (r < V) ? P.mask[r] : 0.f;
    fcb_s[i]  = (r < V) ? P.fcb[r]  : 0.f;
  }
  __syncthreads();

  auto bar64 = [&](unsigned* ctr, unsigned tgt) {
    __threadfence(); __syncthreads();
    if (tid == 0) {
      __hip_atomic_fetch_add(ctr, 1u, __ATOMIC_RELEASE, __HIP_MEMORY_SCOPE_AGENT);
      while (__hip_atomic_load(ctr, __ATOMIC_ACQUIRE, __HIP_MEMORY_SCOPE_AGENT) < tgt)
        __builtin_amdgcn_s_sleep(2);
    }
    __syncthreads(); __threadfence();
  };

  auto chain_run = [&](int r) {
    int selv = 0; float signv = 1.f;
    if (r >= 1) {
      const int par = (r - 1) & 1;
      const float* tkv = par ? P.tkv1 : P.tkv0;
      const int*   tki = par ? P.tki1 : P.tki0;
      float lv[KTOP]; int li[KTOP];
#pragma unroll
      for (int k = 0; k < KTOP; ++k) { lv[k] = NEGBIG; li[k] = SENT_I + k; }
      for (int e = tid; e < NBLK * KTOP; e += 256) {
        float v = tkv[e]; int idx = tki[e];
        if (v > lv[KTOP-1] || (v == lv[KTOP-1] && idx < li[KTOP-1])) {
          lv[KTOP-1] = v; li[KTOP-1] = idx;
#pragma unroll
          for (int k = KTOP - 2; k >= 0; --k) {
            if (lv[k+1] > lv[k] || (lv[k+1] == lv[k] && li[k+1] < li[k])) {
              float tv = lv[k]; lv[k] = lv[k+1]; lv[k+1] = tv;
              int ti = li[k]; li[k] = li[k+1]; li[k+1] = ti;
            }
          }
        }
      }
      for (int k = 0; k < KTOP; ++k) {
        float v = lv[0]; int i = li[0];
        amax64(v, i);
        if (lane == 0) { xwv[w] = v; xwi[w] = i; }
        __syncthreads();
        float bv = xwv[0]; int bi = xwi[0];
#pragma unroll
        for (int j = 1; j < 4; ++j)
          if (xwv[j] > bv || (xwv[j] == bv && xwi[j] < bi)) { bv = xwv[j]; bi = xwi[j]; }
        if (li[0] == bi) {
#pragma unroll
          for (int kk = 0; kk < KTOP - 1; ++kk) { lv[kk] = lv[kk+1]; li[kk] = li[kk+1]; }
          lv[KTOP-1] = NEGBIG; li[KTOP-1] = SENT_I + 900 + k;
        }
        if (tid == 0) g10i[k] = bi;
        __syncthreads();
      }
      if (w == 0) {
        float u = (lane < KTOP) ? P.ui[g10i[lane]] : 0.f;
        unsigned long long ball = __ballot(u > 0.f);
        if (lane == 0) {
          int sv; float sg;
          if (ball) { int k = __ffsll(ball) - 1; sv = g10i[k]; sg = 1.f; }
          else      { sv = g10i[0]; sg = -1.f; }
          sel_sh = sv; sign_sh = sg;
          if (b == 0) {
            P.out_sel[r-1] = (float)sv;
            P.out_hit[r-1] = (sg > 0.f) ? 1.f : 0.f;
            *P.sel_slot = sv; *P.sign_slot = sg;
          }
        }
      }
      __syncthreads();
      selv = sel_sh; signv = sign_sh;
      if (b == 0) {  // invS for step r-1
        const float* sp = par ? P.sp1 : P.sp0;
        float s = 0.f;
        for (int i = tid; i < NBLK; i += 256) s += sp[i];
        s = sum64(s);
        if (lane == 0) red4[w] = s;
        __syncthreads();
        if (tid == 0) P.invS[0] = 1.0f / (red4[0] + red4[1] + red4[2] + red4[3]);
      }
    }
    const int h = b * 4 + w;
    if (r <= T - 1) {  // GRU layer 0 (zero hidden state)
      float4 ev = ((const float4*)(P.emb + (size_t)selv * H))[lane];
      float4 x0 = make_float4(signv*ev.x, signv*ev.y, signv*ev.z, signv*ev.w);
      float4 a0 = ((const float4*)(P.Wih + (size_t)h * H))[lane];
      float4 a1 = ((const float4*)(P.Wih + (size_t)(H + h) * H))[lane];
      float4 a2 = ((const float4*)(P.Wih + (size_t)(2*H + h) * H))[lane];
      float p0 = dot4(a0, x0), p1 = dot4(a1, x0), p2 = dot4(a2, x0);
#pragma unroll
      for (int off = 32; off > 0; off >>= 1) {
        p0 += __shfl_xor(p0, off); p1 += __shfl_xor(p1, off); p2 += __shfl_xor(p2, off);
      }
      if (lane == 0) {
        float rr = sigm(p0 + P.bih[h] + P.bhh[h]);
        float zz = sigm(p1 + P.bih[H+h] + P.bhh[H+h]);
        float nn = tanhf(p2 + P.bih[2*H+h] + rr * P.bhh[2*H+h]);
        P.x1[h] = (1.f - zz) * nn;
      }
    }
    if (r >= 1 && b == NCH - 1 && w == 3) {  // value(r-1) = dot(cell(r-1), valW)+valb
      float4 cv = ((const float4*)P.cellg)[lane];
      float4 vv = ((const float4*)P.valW)[lane];
      float pv = sum64(dot4(cv, vv));
      if (lane == 0) P.out_val[r-1] = pv + P.valb[0];
    }
    bar64(P.bc, 64u * (r + 1));
    if (r <= T - 1) {  // GRU layer 1
      float4 x1v = ((const float4*)P.x1)[lane];
      const float* W1 = P.Wih + 3 * H * H;
      float4 a0 = ((const float4*)(W1 + (size_t)h * H))[lane];
      float4 a1 = ((const float4*)(W1 + (size_t)(H + h) * H))[lane];
      float4 a2 = ((const float4*)(W1 + (size_t)(2*H + h) * H))[lane];
      float p0 = dot4(a0, x1v), p1 = dot4(a1, x1v), p2 = dot4(a2, x1v);
#pragma unroll
      for (int off = 32; off > 0; off >>= 1) {
        p0 += __shfl_xor(p0, off); p1 += __shfl_xor(p1, off); p2 += __shfl_xor(p2, off);
      }
      if (lane == 0) {
        float rr = sigm(p0 + P.bih[3*H+h] + P.bhh[3*H+h]);
        float zz = sigm(p1 + P.bih[4*H+h] + P.bhh[4*H+h]);
        float nn = tanhf(p2 + P.bih[5*H+h] + rr * P.bhh[5*H+h]);
        P.x2[h] = (1.f - zz) * nn;
      }
    }
    bar64(P.cd, 64u * (r + 1));
    if (r <= T - 1) {  // forget gate + cell
      float4 xv = ((const float4*)P.x2)[lane];
      float4 gv = ((const float4*)(P.fgcW + (size_t)h * H))[lane];
      float d = sum64(dot4(gv, xv));
      if (lane == 0) {
        float gt = sigm(P.c1[h] + d);
        P.cellg[h] = gt * P.pm[h] + (1.f - gt) * P.x2[h];
      }
    }
    bar64(P.cellrdy, 64u * (r + 1));
  };

  if (b < NCH) chain_run(0);

  for (int t = 0; t < T; ++t) {
    if (b >= NCH && b < NCH + 32) {         // relay: poll cellrdy, publish group flag
      unsigned tgt = 64u * (t + 1);
      if (tid == 0) {
        while (__hip_atomic_load(P.cellrdy, __ATOMIC_ACQUIRE, __HIP_MEMORY_SCOPE_AGENT) < tgt)
          __builtin_amdgcn_s_sleep(2);
        __hip_atomic_store(&P.relayf[(b - NCH) * 32], (unsigned)(t + 1),
                           __ATOMIC_RELEASE, __HIP_MEMORY_SCOPE_AGENT);
      }
      __syncthreads(); __threadfence();
    } else if (b >= NCH + 32) {             // wait on relay flag
      if (tid == 0) {
        while (__hip_atomic_load(&P.relayf[(b >> 5) * 32], __ATOMIC_ACQUIRE, __HIP_MEMORY_SCOPE_AGENT)
               < (unsigned)(t + 1))
          __builtin_amdgcn_s_sleep(4);
      }
      __syncthreads(); __threadfence();
    }
    // ---- phase A(t): probs(t-1) write, hist update, matvec, top10, Spart ----
    if (tid < 64) ((float4*)cell_s)[tid] = ((const float4*)P.cellg)[tid];
    if (t >= 1) {
      float inv = P.invS[0];
      float* pr = P.probs + (size_t)(t - 1) * V;
      for (int i = tid; i < RPB; i += 256) {
        int r = rowbase + i;
        if (r < V) pr[r] = e_s[i] * inv;
      }
      if (tid == 0) {
        int sv = *(volatile int*)P.sel_slot;
        float sg = *(volatile float*)P.sign_slot;
        if (sg > 0.f && sv >= rowbase && sv < rowbase + RPB) hist_s[sv - rowbase] -= 1.f;
      }
    }
    __syncthreads();
    {
      float4 cq0 = ((float4*)cell_s)[lane16];
      float4 cq1 = ((float4*)cell_s)[lane16 + 16];
      float4 cq2 = ((float4*)cell_s)[lane16 + 32];
      float4 cq3 = ((float4*)cell_s)[lane16 + 48];
#pragma unroll 1
      for (int j = 0; j < 7; ++j) {
        int local = qw + (j << 4);
        int row = rowbase + local;
        float p = 0.f;
        if (local < RPB && row < V) {
          const float4* rp = (const float4*)(P.fcW + (size_t)row * H);
          p = dot4(rp[lane16], cq0) + dot4(rp[lane16 + 16], cq1)
            + dot4(rp[lane16 + 32], cq2) + dot4(rp[lane16 + 48], cq3);
        }
#pragma unroll
        for (int off = 8; off > 0; off >>= 1) p += __shfl_xor(p, off);
        if (lane16 == 0 && local < RPB) {
          if (row < V) {
            float e = expf(p + fcb_s[local]);
            e_s[local] = e; m_s[local] = e * hist_s[local];
          } else { e_s[local] = 0.f; m_s[local] = -1.f; }
        }
      }
    }
    __syncthreads();
    const int par = t & 1;
    {
      float s = 0.f;
      for (int i = tid; i < RPB; i += 256) s += e_s[i];
      s = sum64(s);
      if (lane == 0) red4[w] = s;
      __syncthreads();
      if (tid == 0) (par ? P.sp1 : P.sp0)[b] = red4[0] + red4[1] + red4[2] + red4[3];
    }
    {
      float mv = NEGBIG; int mi = SENT_I + 500 + tid;
      if (w == 0) { mv = m_s[lane]; mi = rowbase + lane; }
      else if (w == 1) {
        int e = 64 + lane;
        if (e < RPB) { mv = m_s[e]; mi = rowbase + e; }
      }
      if (w < 2) {
        for (int k = 0; k < KTOP; ++k) {
          float v = mv; int i = mi;
          amax64(v, i);
          if (lane == 0) { wtv[w * KTOP + k] = v; wti[w * KTOP + k] = i; }
          if (mi == i) mv = NEGBIG;
        }
      }
      __syncthreads();
      if (w == 0) {
        float v2 = NEGBIG; int i2 = SENT_I + 200 + lane;
        if (lane < 2 * KTOP) { v2 = wtv[lane]; i2 = wti[lane]; }
        float* tkvW = par ? P.tkv1 : P.tkv0;
        int*   tkiW = par ? P.tki1 : P.tki0;
        for (int k = 0; k < KTOP; ++k) {
          float v = v2; int i = i2;
          amax64(v, i);
          if (lane == 0) { tkvW[b * KTOP + k] = v; tkiW[b * KTOP + k] = i; }
          if (i2 == i) v2 = NEGBIG;
        }
      }
    }
    __threadfence(); __syncthreads();
    if (tid == 0)
      __hip_atomic_fetch_add(&P.grp[(b >> 5) * 32], 1u, __ATOMIC_RELEASE, __HIP_MEMORY_SCOPE_AGENT);
    if (b < NCH) {
      if (tid < 32) {
        while (__hip_atomic_load(&P.grp[tid * 32], __ATOMIC_ACQUIRE, __HIP_MEMORY_SCOPE_AGENT)
               < 32u * (t + 1))
          __builtin_amdgcn_s_sleep(4);
      }
      __syncthreads(); __threadfence();
      chain_run(t + 1);
    }
  }
  // ---- epilogue: probs(63), final hist ----
  if (b >= NCH && b < NCH + 32) {
    if (tid == 0) {
      while (__hip_atomic_load(P.cellrdy, __ATOMIC_ACQUIRE, __HIP_MEMORY_SCOPE_AGENT) < 64u * (T + 1))
        __builtin_amdgcn_s_sleep(2);
      __hip_atomic_store(&P.relayf[(b - NCH) * 32], (unsigned)(T + 1),
                         __ATOMIC_RELEASE, __HIP_MEMORY_SCOPE_AGENT);
    }
    __syncthreads(); __threadfence();
  } else if (b >= NCH + 32) {
    if (tid == 0) {
      while (__hip_atomic_load(&P.relayf[(b >> 5) * 32], __ATOMIC_ACQUIRE, __HIP_MEMORY_SCOPE_AGENT)
             < (unsigned)(T + 1))
        __builtin_amdgcn_s_sleep(4);
    }
    __syncthreads(); __threadfence();
  }
  {
    float inv = P.invS[0];
    int sv = *(volatile int*)P.sel_slot;
    float sg = *(volatile float*)P.sign_slot;
    float* pr = P.probs + (size_t)(T - 1) * V;
    for (int i = tid; i < RPB; i += 256) {
      int r = rowbase + i;
      if (r < V) {
        float hv = hist_s[i];
        if (sg > 0.f && r == sv) hv -= 1.f;
        P.out_fh[r] = hv;
        pr[r] = e_s[i] * inv;
      }
    }
  }
}

extern "C" void kernel_launch(void* const* d_in, const int* in_sizes, int n_in,
                              void* d_out, int out_size, void* d_ws, size_t ws_size,
                              hipStream_t stream) {
  const float* ui   = (const float*)d_in[0];
  const float* mask = (const float*)d_in[1];
  const float* mem  = (const float*)d_in[2];
  const float* emb  = (const float*)d_in[3];
  const float* Wih  = (const float*)d_in[4];
  const float* bih  = (const float*)d_in[6];
  const float* bhh  = (const float*)d_in[7];
  const float* fcW  = (const float*)d_in[8];
  const float* fcb  = (const float*)d_in[9];
  const float* valW = (const float*)d_in[10];
  const float* valb = (const float*)d_in[11];
  const float* memW = (const float*)d_in[12];
  const float* fgmW = (const float*)d_in[13];
  const float* fgmb = (const float*)d_in[14];
  const float* fgcW = (const float*)d_in[15];

  float* out = (float*)d_out;
  float* probs   = out;
  float* out_sel = out + (size_t)T * V;
  float* out_val = out_sel + T;
  float* out_hit = out_val + T;
  float* out_fh  = out_hit + T;

  float* wsp = (float*)d_ws;
  float* pm   = wsp; wsp += H;
  float* c1b  = wsp; wsp += H;
  float* x1   = wsp; wsp += H;
  float* x2   = wsp; wsp += H;
  float* cell = wsp; wsp += H;
  float* invS = wsp; wsp += 32;
  float* sign_slot = wsp; wsp += 32;
  int*   sel_slot  = (int*)wsp; wsp += 32;
  float* tkv0 = wsp; wsp += NBLK * KTOP;
  float* tkv1 = wsp; wsp += NBLK * KTOP;
  int* tki0 = (int*)wsp; wsp += NBLK * KTOP;
  int* tki1 = (int*)wsp; wsp += NBLK * KTOP;
  float* sp0 = wsp; wsp += NBLK;
  float* sp1 = wsp; wsp += NBLK;
  unsigned* sync = (unsigned*)wsp;

  init_sync<<<9, 256, 0, stream>>>(sync);
  pm_kernel<<<H, 256, 0, stream>>>(mem, memW, pm);
  c1_kernel<<<1, 256, 0, stream>>>(pm, fgmW, fgmb, c1b);

  Params P;
  P.ui = ui; P.mask = mask; P.emb = emb; P.Wih = Wih; P.bih = bih; P.bhh = bhh;
  P.fcW = fcW; P.fcb = fcb; P.valW = valW; P.valb = valb; P.fgcW = fgcW;
  P.pm = pm; P.c1 = c1b; P.x1 = x1; P.x2 = x2; P.cellg = cell;
  P.invS = invS; P.sign_slot = sign_slot; P.sel_slot = sel_slot;
  P.tkv0 = tkv0; P.tkv1 = tkv1; P.tki0 = tki0; P.tki1 = tki1;
  P.sp0 = sp0; P.sp1 = sp1;
  P.grp = sync; P.relayf = sync + 1024; P.cellrdy = sync + 2048;
  P.bc = sync + 2080; P.cd = sync + 2112;
  P.probs = probs; P.out_sel = out_sel; P.out_val = out_val;
  P.out_hit = out_hit; P.out_fh = out_fh;

  void* args[] = { &P };
  hipError_t err = hipLaunchCooperativeKernel(reinterpret_cast<void*>(step_kernel),
                                              dim3(NBLK), dim3(256), args, 0, stream);
  if (err != hipSuccess) {
    // co-residency is expected from __launch_bounds__(256,4): 4 blocks/CU x 256 CUs
    step_kernel<<<dim3(NBLK), dim3(256), 0, stream>>>(P);
  }
}